// Round 3
// baseline (454.998 us; speedup 1.0000x reference)
//
#include <hip/hip_runtime.h>
#include <hip/hip_cooperative_groups.h>
#include <stdint.h>

#define TOK   16384
#define DDIM  1024
#define NEXP  8
#define BM    256
#define BN    256
#define NKT   128           // 8 experts x 16 K-tiles (BK=64)
#define WEPS  1e-5f

typedef __attribute__((ext_vector_type(8))) short  short8;
typedef __attribute__((ext_vector_type(4))) float  floatx4;

// round-to-nearest-even f32 -> bf16 (normal-range data; no NaN path needed)
static __device__ __forceinline__ unsigned int bf16_rne(float f) {
  unsigned int u = __builtin_bit_cast(unsigned int, f);
  return (u + 0x7fffu + ((u >> 16) & 1u)) >> 16;
}
static __device__ __forceinline__ unsigned int pack2(float a, float b) {
  return bf16_rne(a) | (bf16_rne(b) << 16);
}

#define SBAR()      __builtin_amdgcn_s_barrier()
#define WAITLGKM0() asm volatile("s_waitcnt lgkmcnt(0)" ::: "memory")
#define WAITVM4()   asm volatile("s_waitcnt vmcnt(4)" ::: "memory")
#define WAITVM0()   asm volatile("s_waitcnt vmcnt(0)" ::: "memory")

// ---------------------------------------------------------------------------
// Single cooperative kernel: 256 blocks x 512 threads, 1 block/CU.
//
// PREP phase (every block does an identical, balanced slice; no tail):
//   P1: 32 ew-tiles/block (2 teams of 256 thr, LDS 32x33 transpose) ->
//       Bt bf16 chunk-tiled [e][d/16][k/32][16][32], XOR swizzle.
//   P2: 4 token-groups/block (8 waves, wave = (group, k-half)):
//       x -> Xt bf16 chunk-tiled [t/16][k/32][16][32] (same swizzle) while
//       accumulating fp32 gate dots (gw lane-broadcast via L1); c4-shfl +
//       LDS reduce; 64 threads do softmax/threshold/renorm -> w[t][8].
//   threadfence + grid.sync() (device-scope release/acquire: xt/bt/w visible
//   across XCDs; also drains vmcnt so the counted pipeline starts clean).
//
// GEMM phase (unchanged from R1): 256x256 tile, 8 waves, BK=64, 4-phase
// deep pipeline, counted vmcnt(4), setprio around MFMA clusters, Horner
// w-folding with LDS ratio tables, XCD-aware block mapping.
// ---------------------------------------------------------------------------
__global__ __launch_bounds__(512, 2) void moe_fused(
    const float* __restrict__ x,  const float* __restrict__ gw,
    const float* __restrict__ gb, const float* __restrict__ ew,
    const float* __restrict__ eb,
    unsigned short* __restrict__ xt,        // [1024][32][16][32] bf16 swizzled
    unsigned short* __restrict__ bt,        // [8][64][32][16][32] bf16 swizzled
    float* __restrict__ w,                  // [16384][8]
    float* __restrict__ out) {
  __shared__ __align__(16) unsigned char lds[147456];
  float* wtab = (float*)(lds + 131072);   // [256][8] raw gate weights
  float* rtab = (float*)(lds + 139264);   // [8][256]: e<7 ratio w'_e/w'_{e+1}; [7]=w'_7

  const int bid  = blockIdx.x;
  const int tid  = threadIdx.x;
  const int wave = tid >> 6;
  const int lane = tid & 63;

  // ===================== PREP P1: expert_w -> Bt =====================
  {
    const int tt   = tid >> 8;           // team 0/1
    const int ttid = tid & 255;
    const int c4 = ttid & 7;
    const int r  = ttid >> 3;
    float (*tile)[33] = (float (*)[33])(lds + tt * 4224);
    for (int it = 0; it < 16; ++it) {
      int idx = bid * 32 + it * 2 + tt;  // 0..8191 tile id
      int e = idx >> 10, rem = idx & 1023;
      int k0 = ((rem >> 5) & 31) * 32, d0 = (rem & 31) * 32;
      const float* src = ew + ((size_t)e << 20) + (size_t)(k0 + r) * DDIM + d0 + c4 * 4;
      float4 v = *(const float4*)src;
      tile[r][c4 * 4 + 0] = v.x;
      tile[r][c4 * 4 + 1] = v.y;
      tile[r][c4 * 4 + 2] = v.z;
      tile[r][c4 * 4 + 3] = v.w;
      __syncthreads();
      uint2 pk;
      pk.x = pack2(tile[c4 * 4 + 0][r], tile[c4 * 4 + 1][r]);
      pk.y = pack2(tile[c4 * 4 + 2][r], tile[c4 * 4 + 3][r]);
      int d = d0 + r, d16 = d >> 4, r16 = d & 15, k32 = k0 >> 5, kc = c4 * 4;
      int rot = ((r16 >> 1) & 3) * 8;
      *(uint2*)(bt + ((((size_t)e * 64 + d16) * 32 + k32) << 9) + r16 * 32 + (kc ^ rot)) = pk;
      __syncthreads();
    }
  }

  // ===================== PREP P2: x -> Xt + gate =====================
  {
    float* gred = (float*)(lds + 8448);  // [8 waves][16 rows][8 experts]
    const int m16   = bid * 4 + (wave >> 1);
    const int khalf = wave & 1;
    const int r   = lane >> 2;           // token row within chunk
    const int c4  = lane & 3;            // 8-element col group
    const int rot = ((r >> 1) & 3) * 8;

    float gacc[8];
#pragma unroll
    for (int e = 0; e < 8; ++e) gacc[e] = 0.f;

    for (int i = 0; i < 16; ++i) {
      int k32 = khalf * 16 + i;
      const float* src = x + (size_t)(m16 * 16 + r) * DDIM + k32 * 32 + c4 * 8;
      float4 v0 = *(const float4*)src;
      float4 v1 = *(const float4*)(src + 4);

      const float* gr = gw + (size_t)(k32 * 32 + c4 * 8) * 8;
      float xv0 = v0.x, xv1 = v0.y, xv2 = v0.z, xv3 = v0.w;
      float xv4 = v1.x, xv5 = v1.y, xv6 = v1.z, xv7 = v1.w;
#pragma unroll
      for (int j = 0; j < 8; ++j) {
        float xv = (j == 0) ? xv0 : (j == 1) ? xv1 : (j == 2) ? xv2 : (j == 3) ? xv3
                 : (j == 4) ? xv4 : (j == 5) ? xv5 : (j == 6) ? xv6 : xv7;
        const float4* g = (const float4*)(gr + j * 8);
        float4 g0 = g[0];
        float4 g1 = g[1];
        gacc[0] += xv * g0.x; gacc[1] += xv * g0.y;
        gacc[2] += xv * g0.z; gacc[3] += xv * g0.w;
        gacc[4] += xv * g1.x; gacc[5] += xv * g1.y;
        gacc[6] += xv * g1.z; gacc[7] += xv * g1.w;
      }

      uint4 pk;
      pk.x = pack2(v0.x, v0.y); pk.y = pack2(v0.z, v0.w);
      pk.z = pack2(v1.x, v1.y); pk.w = pack2(v1.z, v1.w);
      *(uint4*)(xt + ((size_t)(m16 * 32 + k32) << 9) + r * 32 + ((c4 * 8) ^ rot)) = pk;
    }

    // reduce over c4 lanes (bits 0-1 of lane)
#pragma unroll
    for (int e = 0; e < 8; ++e) {
      gacc[e] += __shfl_xor(gacc[e], 1, 64);
      gacc[e] += __shfl_xor(gacc[e], 2, 64);
    }
    if (c4 == 0) {
#pragma unroll
      for (int e = 0; e < 8; ++e) gred[(wave * 16 + r) * 8 + e] = gacc[e];
    }
    __syncthreads();

    if (tid < 64) {
      int g = tid >> 4, row = tid & 15;
      int t = (bid * 4 + g) * 16 + row;
      float logit[8], m = -1e30f;
#pragma unroll
      for (int e = 0; e < 8; ++e) {
        logit[e] = gred[((g * 2) * 16 + row) * 8 + e] +
                   gred[((g * 2 + 1) * 16 + row) * 8 + e] + gb[e];
        m = fmaxf(m, logit[e]);
      }
      float p[8], s = 0.f;
#pragma unroll
      for (int e = 0; e < 8; ++e) { p[e] = expf(logit[e] - m); s += p[e]; }
      float wv[8], wsum = 0.f;
#pragma unroll
      for (int e = 0; e < 8; ++e) {
        float pr = p[e] / s;
        wv[e] = (pr >= 0.1f) ? pr : 0.f;
        wsum += wv[e];
      }
      float invw = (wsum == 0.f) ? 1.f : (1.f / wsum);
#pragma unroll
      for (int e = 0; e < 8; ++e) w[(size_t)t * 8 + e] = wv[e] * invw;
    }
  }

  // device-scope release; grid-wide barrier (acquire side invalidates stale
  // cross-XCD cache lines; also drains vmcnt -> counted pipeline starts clean)
  __threadfence();
  cooperative_groups::this_grid().sync();

  // ===================== GEMM phase (unchanged from R1) =====================
  // XCD-aware mapping: 256 blocks, xcd = wgid%8 owns contiguous bm chunk
  const int wgid = bid;
  const int xcd  = wgid & 7;
  const int idx  = wgid >> 3;              // 0..31
  const int bm0  = (xcd * 8 + (idx & 7)) * BM;
  const int bn0  = (idx >> 3) * BN;
  const int bm16 = bm0 >> 4;
  const int bn16 = bn0 >> 4;

  const int wm  = (wave >> 2) * 128;       // wave's A half (2M x 4N wave grid)
  const int wn  = (wave & 3) * 64;
  const int fr  = lane & 15;
  const int q8  = (lane >> 4) * 8;
  const int qby = (fr * 32 + (q8 ^ (((fr >> 1) & 3) * 8))) * 2;  // swizzled byte off

  // ---- prologue: w tables (plain VMEM drained before pipeline starts) ----
  ((float4*)wtab)[tid] = ((const float4*)(w + (size_t)bm0 * 8))[tid];
  __syncthreads();
  {
    const int t  = tid & 255;
    const int e0 = (tid >> 8) * 4;
#pragma unroll
    for (int i = 0; i < 4; ++i) {
      int e = e0 + i;
      float wc = fmaxf(wtab[t * 8 + e], WEPS);
      float r  = wc;
      if (e < 7) r = wc * __builtin_amdgcn_rcpf(fmaxf(wtab[t * 8 + e + 1], WEPS));
      rtab[e * 256 + t] = r;
    }
  }
  __syncthreads();

  // half-tile stagers: 2 x global_load_lds(16B) per wave; wave w owns chunk h*8+w
  auto stageA = [&](int h, int kt) {
    if (kt >= NKT) return;
    const int b = kt & 1;
    const size_t mc = (size_t)(bm16 + h * 8 + wave) * 32 + (kt & 15) * 2;
#pragma unroll
    for (int ks = 0; ks < 2; ++ks) {
      __builtin_amdgcn_global_load_lds(
          (const __attribute__((address_space(1))) unsigned int*)(xt + ((mc + ks) << 9) + lane * 8),
          (__attribute__((address_space(3))) unsigned int*)(lds + b * 65536 + ((h * 8 + wave) * 2 + ks) * 1024),
          16, 0, 0);
    }
  };
  auto stageB = [&](int h, int kt) {
    if (kt >= NKT) return;
    const int b = kt & 1;
    const size_t dc = (size_t)((kt >> 4) * 64 + bn16 + h * 8 + wave) * 32 + (kt & 15) * 2;
#pragma unroll
    for (int ks = 0; ks < 2; ++ks) {
      __builtin_amdgcn_global_load_lds(
          (const __attribute__((address_space(1))) unsigned int*)(bt + ((dc + ks) << 9) + lane * 8),
          (__attribute__((address_space(3))) unsigned int*)(lds + b * 65536 + 32768 + ((h * 8 + wave) * 2 + ks) * 1024),
          16, 0, 0);
    }
  };
  auto AF = [&](int b, int mh, int mi, int ks) -> short8 {
    return *(const short8*)(lds + b * 65536 +
        ((((wave >> 2) * 8 + mh * 4 + mi) * 2 + ks) << 10) + qby);
  };
  auto BF = [&](int b, int nh, int ni, int ks) -> short8 {
    return *(const short8*)(lds + b * 65536 + 32768 +
        ((((wave & 3) * 4 + nh * 2 + ni) * 2 + ks) << 10) + qby);
  };

  floatx4 acc[8][4];
#pragma unroll
  for (int mi = 0; mi < 8; ++mi)
#pragma unroll
    for (int ni = 0; ni < 4; ++ni) acc[mi][ni] = (floatx4)0.f;

  // pipeline prologue: tile0 complete + B halves of tile1 left in flight
  stageA(0, 0); stageA(1, 0); stageB(0, 0); stageB(1, 0);
  stageB(0, 1); stageB(1, 1);
  WAITVM4();          // 12 issued, <=4 outstanding -> tile0's 8 landed
  SBAR();

  auto tile = [&](int kt, int b) {
    short8 af[4][2], b0[2][2], b1[2][2];

    // -- phase 1: Q(m-half0, n-half0) --
#pragma unroll
    for (int mi = 0; mi < 4; ++mi) { af[mi][0] = AF(b, 0, mi, 0); af[mi][1] = AF(b, 0, mi, 1); }
#pragma unroll
    for (int ni = 0; ni < 2; ++ni) { b0[ni][0] = BF(b, 0, ni, 0); b0[ni][1] = BF(b, 0, ni, 1); }
    stageA(0, kt + 1);
    SBAR(); WAITLGKM0();
    __builtin_amdgcn_s_setprio(1);
#pragma unroll
    for (int mi = 0; mi < 4; ++mi)
#pragma unroll
      for (int ni = 0; ni < 2; ++ni)
#pragma unroll
        for (int ks = 0; ks < 2; ++ks)
          acc[mi][ni] = __builtin_amdgcn_mfma_f32_16x16x32_bf16(af[mi][ks], b0[ni][ks], acc[mi][ni], 0, 0, 0);
    __builtin_amdgcn_s_setprio(0);
    SBAR();

    // -- phase 2: Q(m-half0, n-half1) --
#pragma unroll
    for (int ni = 0; ni < 2; ++ni) { b1[ni][0] = BF(b, 1, ni, 0); b1[ni][1] = BF(b, 1, ni, 1); }
    stageA(1, kt + 1);
    SBAR(); WAITLGKM0();
    __builtin_amdgcn_s_setprio(1);
#pragma unroll
    for (int mi = 0; mi < 4; ++mi)
#pragma unroll
      for (int ni = 0; ni < 2; ++ni)
#pragma unroll
        for (int ks = 0; ks < 2; ++ks)
          acc[mi][ni + 2] = __builtin_amdgcn_mfma_f32_16x16x32_bf16(af[mi][ks], b1[ni][ks], acc[mi][ni + 2], 0, 0, 0);
    __builtin_amdgcn_s_setprio(0);
    SBAR();

    // -- phase 3: Q(m-half1, n-half0); B regions of this buf now free --
#pragma unroll
    for (int mi = 0; mi < 4; ++mi) { af[mi][0] = AF(b, 1, mi, 0); af[mi][1] = AF(b, 1, mi, 1); }
    stageB(0, kt + 2);
    SBAR(); WAITLGKM0();
    __builtin_amdgcn_s_setprio(1);
#pragma unroll
    for (int mi = 0; mi < 4; ++mi)
#pragma unroll
      for (int ni = 0; ni < 2; ++ni)
#pragma unroll
        for (int ks = 0; ks < 2; ++ks)
          acc[mi + 4][ni] = __builtin_amdgcn_mfma_f32_16x16x32_bf16(af[mi][ks], b0[ni][ks], acc[mi + 4][ni], 0, 0, 0);
    __builtin_amdgcn_s_setprio(0);
    SBAR();

    // -- phase 4: Q(m-half1, n-half1); tile-boundary counted wait --
    stageB(1, kt + 2);
    SBAR();
    __builtin_amdgcn_s_setprio(1);
#pragma unroll
    for (int mi = 0; mi < 4; ++mi)
#pragma unroll
      for (int ni = 0; ni < 2; ++ni)
#pragma unroll
        for (int ks = 0; ks < 2; ++ks)
          acc[mi + 4][ni + 2] = __builtin_amdgcn_mfma_f32_16x16x32_bf16(af[mi][ks], b1[ni][ks], acc[mi + 4][ni + 2], 0, 0, 0);
    __builtin_amdgcn_s_setprio(0);
    if (kt < NKT - 2) { WAITVM4(); } else { WAITVM0(); }
    SBAR();

    // -- Horner boundary: acc *= w'_e / w'_{e+1} (from LDS table) --
    if ((kt & 15) == 15 && kt < NKT - 1) {
      const int e  = kt >> 4;
      const int rb = e * 256 + wm + (lane >> 4) * 4;
#pragma unroll
      for (int mi = 0; mi < 8; ++mi) {
        floatx4 rv = *(const floatx4*)(rtab + rb + mi * 16);
#pragma unroll
        for (int ni = 0; ni < 4; ++ni)
#pragma unroll
          for (int rr = 0; rr < 4; ++rr) acc[mi][ni][rr] *= rv[rr];
      }
    }
  };

  for (int kt2 = 0; kt2 < NKT / 2; ++kt2) {
    tile(kt2 * 2, 0);
    tile(kt2 * 2 + 1, 1);
  }

  // keep the epilogue VMEM (eb loads) from hoisting into the counted pipeline
  asm volatile("" ::: "memory");

  // ---- epilogue: out = acc * w'_7 + sum_e w_e * eb_e ----
  float ebv[8][4];
#pragma unroll
  for (int e = 0; e < 8; ++e)
#pragma unroll
    for (int ni = 0; ni < 4; ++ni)
      ebv[e][ni] = eb[(size_t)e * DDIM + bn0 + wn + ni * 16 + fr];

#pragma unroll
  for (int mi = 0; mi < 8; ++mi) {
    const int tl0 = wm + mi * 16 + (lane >> 4) * 4;
    floatx4 w7v = *(const floatx4*)(rtab + 7 * 256 + tl0);
#pragma unroll
    for (int rr = 0; rr < 4; ++rr) {
      const int tl = tl0 + rr;
      floatx4 w0 = *(const floatx4*)(wtab + tl * 8);
      floatx4 w1 = *(const floatx4*)(wtab + tl * 8 + 4);
      float* orow = out + (size_t)(bm0 + tl) * DDIM + bn0 + wn + fr;
#pragma unroll
      for (int ni = 0; ni < 4; ++ni) {
        float bias = w0[0] * ebv[0][ni] + w0[1] * ebv[1][ni] +
                     w0[2] * ebv[2][ni] + w0[3] * ebv[3][ni] +
                     w1[0] * ebv[4][ni] + w1[1] * ebv[5][ni] +
                     w1[2] * ebv[6][ni] + w1[3] * ebv[7][ni];
        orow[ni * 16] = acc[mi][ni][rr] * w7v[rr] + bias;
      }
    }
  }
}

// ---------------------------------------------------------------------------
extern "C" void kernel_launch(void* const* d_in, const int* in_sizes, int n_in,
                              void* d_out, int out_size, void* d_ws, size_t ws_size,
                              hipStream_t stream) {
  const float* x  = (const float*)d_in[0];   // [4,4096,1024]
  const float* gw = (const float*)d_in[1];   // [1024,8]
  const float* gb = (const float*)d_in[2];   // [8]
  const float* ew = (const float*)d_in[3];   // [8,1024,1024]
  const float* eb = (const float*)d_in[4];   // [8,1024]
  float* out = (float*)d_out;

  // ws: w[16384*8] fp32 (512 KB) | Xt bf16 (32 MB) | Bt bf16 (16 MB)
  float* wbuf = (float*)d_ws;
  unsigned short* xtp = (unsigned short*)((char*)d_ws + (size_t)TOK * 8 * 4);
  unsigned short* btp = xtp + (size_t)TOK * DDIM;

  void* args[] = {(void*)&x, (void*)&gw, (void*)&gb, (void*)&ew, (void*)&eb,
                  (void*)&xtp, (void*)&btp, (void*)&wbuf, (void*)&out};
  hipLaunchCooperativeKernel((const void*)moe_fused, dim3(256), dim3(512),
                             args, 0, stream);
}

// Round 4
// 392.198 us; speedup vs baseline: 1.1601x; 1.1601x over previous
//
#include <hip/hip_runtime.h>
#include <stdint.h>

#define TOK   16384
#define DDIM  1024
#define NEXP  8
#define BM    256
#define BN    256
#define NKT   128           // 8 experts x 16 K-tiles (BK=64)
#define WEPS  1e-5f

typedef __attribute__((ext_vector_type(8))) short  short8;
typedef __attribute__((ext_vector_type(4))) float  floatx4;

// round-to-nearest-even f32 -> bf16 (normal-range data; no NaN path needed)
static __device__ __forceinline__ unsigned int bf16_rne(float f) {
  unsigned int u = __builtin_bit_cast(unsigned int, f);
  return (u + 0x7fffu + ((u >> 16) & 1u)) >> 16;
}
static __device__ __forceinline__ unsigned int pack2(float a, float b) {
  return bf16_rne(a) | (bf16_rne(b) << 16);
}

// ---------------------------------------------------------------------------
// Kernel 1: fused gate + prep_x. One block per 16 tokens, 4 waves; wave w
// covers k32 = w*8 .. w*8+7. Single pass over x: converts to Xt bf16
// chunk-tiled [t/16][k/32][16][32] (XOR swizzle) while accumulating fp32 gate
// dots (gw reads are 16-lane same-address -> L1 broadcast). c4-shfl + LDS
// reduce, then 16 threads do softmax/threshold/renorm -> w[t][8].
// Removes the separate gate kernel's second 64 MB read of x + one launch.
// ---------------------------------------------------------------------------
__global__ __launch_bounds__(256) void gate_prep_x(
    const float* __restrict__ x,  const float* __restrict__ gw,
    const float* __restrict__ gb, unsigned short* __restrict__ xt,
    float* __restrict__ wout) {
  __shared__ float gred[4 * 16 * 8];
  const int m16  = blockIdx.x;
  const int tid  = threadIdx.x;
  const int wave = tid >> 6;
  const int lane = tid & 63;
  const int r   = lane >> 2;             // token row within chunk
  const int c4  = lane & 3;              // 8-element col group
  const int rot = ((r >> 1) & 3) * 8;

  float acc[8];
#pragma unroll
  for (int e = 0; e < 8; ++e) acc[e] = 0.f;

#pragma unroll
  for (int i = 0; i < 8; ++i) {
    int k32 = wave * 8 + i;
    const float* src = x + (size_t)(m16 * 16 + r) * DDIM + k32 * 32 + c4 * 8;
    float4 v0 = *(const float4*)src;
    float4 v1 = *(const float4*)(src + 4);

    // gate partials: k = k32*32 + c4*8 + j ; same-address across 16 lanes
    const float* gr = gw + (size_t)(k32 * 32 + c4 * 8) * 8;
    float xv0 = v0.x, xv1 = v0.y, xv2 = v0.z, xv3 = v0.w;
    float xv4 = v1.x, xv5 = v1.y, xv6 = v1.z, xv7 = v1.w;
#pragma unroll
    for (int j = 0; j < 8; ++j) {
      float xv = (j == 0) ? xv0 : (j == 1) ? xv1 : (j == 2) ? xv2 : (j == 3) ? xv3
               : (j == 4) ? xv4 : (j == 5) ? xv5 : (j == 6) ? xv6 : xv7;
      const float4* g = (const float4*)(gr + j * 8);
      float4 g0 = g[0];
      float4 g1 = g[1];
      acc[0] += xv * g0.x; acc[1] += xv * g0.y;
      acc[2] += xv * g0.z; acc[3] += xv * g0.w;
      acc[4] += xv * g1.x; acc[5] += xv * g1.y;
      acc[6] += xv * g1.z; acc[7] += xv * g1.w;
    }

    uint4 pk;
    pk.x = pack2(v0.x, v0.y); pk.y = pack2(v0.z, v0.w);
    pk.z = pack2(v1.x, v1.y); pk.w = pack2(v1.z, v1.w);
    *(uint4*)(xt + ((size_t)(m16 * 32 + k32) << 9) + r * 32 + ((c4 * 8) ^ rot)) = pk;
  }

  // reduce over c4 lanes (bits 0-1 of lane)
#pragma unroll
  for (int e = 0; e < 8; ++e) {
    acc[e] += __shfl_xor(acc[e], 1, 64);
    acc[e] += __shfl_xor(acc[e], 2, 64);
  }
  if (c4 == 0) {
#pragma unroll
    for (int e = 0; e < 8; ++e) gred[(wave * 16 + r) * 8 + e] = acc[e];
  }
  __syncthreads();

  if (tid < 16) {
    int t = m16 * 16 + tid;
    float logit[8], m = -1e30f;
#pragma unroll
    for (int e = 0; e < 8; ++e) {
      logit[e] = gred[(0 * 16 + tid) * 8 + e] + gred[(1 * 16 + tid) * 8 + e] +
                 gred[(2 * 16 + tid) * 8 + e] + gred[(3 * 16 + tid) * 8 + e] + gb[e];
      m = fmaxf(m, logit[e]);
    }
    float p[8], s = 0.f;
#pragma unroll
    for (int e = 0; e < 8; ++e) { p[e] = expf(logit[e] - m); s += p[e]; }
    float wv[8], wsum = 0.f;
#pragma unroll
    for (int e = 0; e < 8; ++e) {
      float pr = p[e] / s;
      wv[e] = (pr >= 0.1f) ? pr : 0.f;
      wsum += wv[e];
    }
    float invw = (wsum == 0.f) ? 1.f : (1.f / wsum);
#pragma unroll
    for (int e = 0; e < 8; ++e) wout[(size_t)t * 8 + e] = wv[e] * invw;
  }
}

// ---------------------------------------------------------------------------
// Kernel 2: expert_w fp32 [e][k][d] -> Bt bf16 chunk-tiled
// [e][d/16][k/32][16][32] with the same XOR swizzle (transpose via LDS tile).
// ---------------------------------------------------------------------------
__global__ __launch_bounds__(256) void prep_w(
    const float* __restrict__ ew, unsigned short* __restrict__ bt) {
  __shared__ float tile[32][33];
  int e  = blockIdx.z;
  int k0 = blockIdx.y * 32;
  int d0 = blockIdx.x * 32;
  int c4 = threadIdx.x & 7;
  int r  = threadIdx.x >> 3;

  const float* src = ew + ((size_t)e << 20) + (size_t)(k0 + r) * DDIM + d0 + c4 * 4;
  float4 v = *(const float4*)src;
  tile[r][c4 * 4 + 0] = v.x;
  tile[r][c4 * 4 + 1] = v.y;
  tile[r][c4 * 4 + 2] = v.z;
  tile[r][c4 * 4 + 3] = v.w;
  __syncthreads();

  uint2 pk;
  pk.x = pack2(tile[c4 * 4 + 0][r], tile[c4 * 4 + 1][r]);
  pk.y = pack2(tile[c4 * 4 + 2][r], tile[c4 * 4 + 3][r]);
  int d   = d0 + r;                  // output row (n), cols k = k0+c4*4 .. +3
  int d16 = d >> 4, r16 = d & 15, k32 = k0 >> 5, kc = c4 * 4;
  int rot = ((r16 >> 1) & 3) * 8;
  *(uint2*)(bt + ((((size_t)e * 64 + d16) * 32 + k32) << 9) + r16 * 32 + (kc ^ rot)) = pk;
}

// ---------------------------------------------------------------------------
// Kernel 3: MoE GEMM (byte-identical to R1's proven 234.5 µs version).
// 256x256 tile, 8 waves, BK=64, 4-phase/K-tile deep pipeline (T3+T4): raw
// s_barrier, counted vmcnt(4) once per K-tile (never 0 in the loop),
// setprio(1) around each 16-MFMA quadrant cluster (T5). Horner w-folding
// with LDS ratio tables; no plain VMEM in the main loop. XCD-aware mapping.
// ---------------------------------------------------------------------------
#define SBAR()      __builtin_amdgcn_s_barrier()
#define WAITLGKM0() asm volatile("s_waitcnt lgkmcnt(0)" ::: "memory")
#define WAITVM4()   asm volatile("s_waitcnt vmcnt(4)" ::: "memory")
#define WAITVM0()   asm volatile("s_waitcnt vmcnt(0)" ::: "memory")

__global__ __launch_bounds__(512, 2) void moe_gemm(
    const unsigned short* __restrict__ xt,  // [1024][32][16][32] bf16 swizzled
    const float* __restrict__ w,            // [16384][8]
    const unsigned short* __restrict__ bt,  // [8][64][32][16][32] bf16 swizzled
    const float* __restrict__ eb, float* __restrict__ out) {
  // 2 x 64KB tile buffers (A 32 chunks + B 32 chunks, 1KB each) + w tables
  __shared__ __align__(16) unsigned char lds[147456];
  float* wtab = (float*)(lds + 131072);   // [256][8] raw gate weights
  float* rtab = (float*)(lds + 139264);   // [8][256]: e<7 ratio w'_e/w'_{e+1}; [7]=w'_7

  const int tid  = threadIdx.x;
  const int wave = tid >> 6;
  const int lane = tid & 63;

  // XCD-aware mapping: 256 blocks, xcd = wgid%8 owns contiguous bm chunk
  const int wgid = blockIdx.x;
  const int xcd  = wgid & 7;
  const int idx  = wgid >> 3;              // 0..31
  const int bm0  = (xcd * 8 + (idx & 7)) * BM;
  const int bn0  = (idx >> 3) * BN;
  const int bm16 = bm0 >> 4;
  const int bn16 = bn0 >> 4;

  const int wm  = (wave >> 2) * 128;       // wave's A half (2M x 4N wave grid)
  const int wn  = (wave & 3) * 64;
  const int fr  = lane & 15;
  const int q8  = (lane >> 4) * 8;
  const int qby = (fr * 32 + (q8 ^ (((fr >> 1) & 3) * 8))) * 2;  // swizzled byte off

  // ---- prologue: w tables (ALL plain VMEM drained before pipeline starts) ----
  ((float4*)wtab)[tid] = ((const float4*)(w + (size_t)bm0 * 8))[tid];
  __syncthreads();
  {
    const int t  = tid & 255;
    const int e0 = (tid >> 8) * 4;
#pragma unroll
    for (int i = 0; i < 4; ++i) {
      int e = e0 + i;
      float wc = fmaxf(wtab[t * 8 + e], WEPS);
      float r  = wc;
      if (e < 7) r = wc * __builtin_amdgcn_rcpf(fmaxf(wtab[t * 8 + e + 1], WEPS));
      rtab[e * 256 + t] = r;
    }
  }
  __syncthreads();

  // half-tile stagers: 2 x global_load_lds(16B) per wave; wave w owns chunk h*8+w
  auto stageA = [&](int h, int kt) {
    if (kt >= NKT) return;
    const int b = kt & 1;
    const size_t mc = (size_t)(bm16 + h * 8 + wave) * 32 + (kt & 15) * 2;
#pragma unroll
    for (int ks = 0; ks < 2; ++ks) {
      __builtin_amdgcn_global_load_lds(
          (const __attribute__((address_space(1))) unsigned int*)(xt + ((mc + ks) << 9) + lane * 8),
          (__attribute__((address_space(3))) unsigned int*)(lds + b * 65536 + ((h * 8 + wave) * 2 + ks) * 1024),
          16, 0, 0);
    }
  };
  auto stageB = [&](int h, int kt) {
    if (kt >= NKT) return;
    const int b = kt & 1;
    const size_t dc = (size_t)((kt >> 4) * 64 + bn16 + h * 8 + wave) * 32 + (kt & 15) * 2;
#pragma unroll
    for (int ks = 0; ks < 2; ++ks) {
      __builtin_amdgcn_global_load_lds(
          (const __attribute__((address_space(1))) unsigned int*)(bt + ((dc + ks) << 9) + lane * 8),
          (__attribute__((address_space(3))) unsigned int*)(lds + b * 65536 + 32768 + ((h * 8 + wave) * 2 + ks) * 1024),
          16, 0, 0);
    }
  };
  auto AF = [&](int b, int mh, int mi, int ks) -> short8 {
    return *(const short8*)(lds + b * 65536 +
        ((((wave >> 2) * 8 + mh * 4 + mi) * 2 + ks) << 10) + qby);
  };
  auto BF = [&](int b, int nh, int ni, int ks) -> short8 {
    return *(const short8*)(lds + b * 65536 + 32768 +
        ((((wave & 3) * 4 + nh * 2 + ni) * 2 + ks) << 10) + qby);
  };

  floatx4 acc[8][4];
#pragma unroll
  for (int mi = 0; mi < 8; ++mi)
#pragma unroll
    for (int ni = 0; ni < 4; ++ni) acc[mi][ni] = (floatx4)0.f;

  // pipeline prologue: tile0 complete + B halves of tile1 left in flight
  stageA(0, 0); stageA(1, 0); stageB(0, 0); stageB(1, 0);
  stageB(0, 1); stageB(1, 1);
  WAITVM4();          // 12 issued, <=4 outstanding -> tile0's 8 landed
  SBAR();

  auto tile = [&](int kt, int b) {
    short8 af[4][2], b0[2][2], b1[2][2];

    // -- phase 1: Q(m-half0, n-half0) --
#pragma unroll
    for (int mi = 0; mi < 4; ++mi) { af[mi][0] = AF(b, 0, mi, 0); af[mi][1] = AF(b, 0, mi, 1); }
#pragma unroll
    for (int ni = 0; ni < 2; ++ni) { b0[ni][0] = BF(b, 0, ni, 0); b0[ni][1] = BF(b, 0, ni, 1); }
    stageA(0, kt + 1);
    SBAR(); WAITLGKM0();
    __builtin_amdgcn_s_setprio(1);
#pragma unroll
    for (int mi = 0; mi < 4; ++mi)
#pragma unroll
      for (int ni = 0; ni < 2; ++ni)
#pragma unroll
        for (int ks = 0; ks < 2; ++ks)
          acc[mi][ni] = __builtin_amdgcn_mfma_f32_16x16x32_bf16(af[mi][ks], b0[ni][ks], acc[mi][ni], 0, 0, 0);
    __builtin_amdgcn_s_setprio(0);
    SBAR();

    // -- phase 2: Q(m-half0, n-half1) --
#pragma unroll
    for (int ni = 0; ni < 2; ++ni) { b1[ni][0] = BF(b, 1, ni, 0); b1[ni][1] = BF(b, 1, ni, 1); }
    stageA(1, kt + 1);
    SBAR(); WAITLGKM0();
    __builtin_amdgcn_s_setprio(1);
#pragma unroll
    for (int mi = 0; mi < 4; ++mi)
#pragma unroll
      for (int ni = 0; ni < 2; ++ni)
#pragma unroll
        for (int ks = 0; ks < 2; ++ks)
          acc[mi][ni + 2] = __builtin_amdgcn_mfma_f32_16x16x32_bf16(af[mi][ks], b1[ni][ks], acc[mi][ni + 2], 0, 0, 0);
    __builtin_amdgcn_s_setprio(0);
    SBAR();

    // -- phase 3: Q(m-half1, n-half0); B regions of this buf now free --
#pragma unroll
    for (int mi = 0; mi < 4; ++mi) { af[mi][0] = AF(b, 1, mi, 0); af[mi][1] = AF(b, 1, mi, 1); }
    stageB(0, kt + 2);
    SBAR(); WAITLGKM0();
    __builtin_amdgcn_s_setprio(1);
#pragma unroll
    for (int mi = 0; mi < 4; ++mi)
#pragma unroll
      for (int ni = 0; ni < 2; ++ni)
#pragma unroll
        for (int ks = 0; ks < 2; ++ks)
          acc[mi + 4][ni] = __builtin_amdgcn_mfma_f32_16x16x32_bf16(af[mi][ks], b0[ni][ks], acc[mi + 4][ni], 0, 0, 0);
    __builtin_amdgcn_s_setprio(0);
    SBAR();

    // -- phase 4: Q(m-half1, n-half1); tile-boundary counted wait --
    stageB(1, kt + 2);
    SBAR();
    __builtin_amdgcn_s_setprio(1);
#pragma unroll
    for (int mi = 0; mi < 4; ++mi)
#pragma unroll
      for (int ni = 0; ni < 2; ++ni)
#pragma unroll
        for (int ks = 0; ks < 2; ++ks)
          acc[mi + 4][ni + 2] = __builtin_amdgcn_mfma_f32_16x16x32_bf16(af[mi][ks], b1[ni][ks], acc[mi + 4][ni + 2], 0, 0, 0);
    __builtin_amdgcn_s_setprio(0);
    if (kt < NKT - 2) { WAITVM4(); } else { WAITVM0(); }
    SBAR();

    // -- Horner boundary: acc *= w'_e / w'_{e+1} (from LDS table) --
    if ((kt & 15) == 15 && kt < NKT - 1) {
      const int e  = kt >> 4;
      const int rb = e * 256 + wm + (lane >> 4) * 4;
#pragma unroll
      for (int mi = 0; mi < 8; ++mi) {
        floatx4 rv = *(const floatx4*)(rtab + rb + mi * 16);
#pragma unroll
        for (int ni = 0; ni < 4; ++ni)
#pragma unroll
          for (int rr = 0; rr < 4; ++rr) acc[mi][ni][rr] *= rv[rr];
      }
    }
  };

  for (int kt2 = 0; kt2 < NKT / 2; ++kt2) {
    tile(kt2 * 2, 0);
    tile(kt2 * 2 + 1, 1);
  }

  // keep the epilogue VMEM (eb loads) from hoisting into the counted pipeline
  asm volatile("" ::: "memory");

  // ---- epilogue: out = acc * w'_7 + sum_e w_e * eb_e ----
  float ebv[8][4];
#pragma unroll
  for (int e = 0; e < 8; ++e)
#pragma unroll
    for (int ni = 0; ni < 4; ++ni)
      ebv[e][ni] = eb[(size_t)e * DDIM + bn0 + wn + ni * 16 + fr];

#pragma unroll
  for (int mi = 0; mi < 8; ++mi) {
    const int tl0 = wm + mi * 16 + (lane >> 4) * 4;
    floatx4 w7v = *(const floatx4*)(rtab + 7 * 256 + tl0);
#pragma unroll
    for (int rr = 0; rr < 4; ++rr) {
      const int tl = tl0 + rr;
      floatx4 w0 = *(const floatx4*)(wtab + tl * 8);
      floatx4 w1 = *(const floatx4*)(wtab + tl * 8 + 4);
      float* orow = out + (size_t)(bm0 + tl) * DDIM + bn0 + wn + fr;
#pragma unroll
      for (int ni = 0; ni < 4; ++ni) {
        float bias = w0[0] * ebv[0][ni] + w0[1] * ebv[1][ni] +
                     w0[2] * ebv[2][ni] + w0[3] * ebv[3][ni] +
                     w1[0] * ebv[4][ni] + w1[1] * ebv[5][ni] +
                     w1[2] * ebv[6][ni] + w1[3] * ebv[7][ni];
        orow[ni * 16] = acc[mi][ni][rr] * w7v[rr] + bias;
      }
    }
  }
}

// ---------------------------------------------------------------------------
extern "C" void kernel_launch(void* const* d_in, const int* in_sizes, int n_in,
                              void* d_out, int out_size, void* d_ws, size_t ws_size,
                              hipStream_t stream) {
  const float* x  = (const float*)d_in[0];   // [4,4096,1024]
  const float* gw = (const float*)d_in[1];   // [1024,8]
  const float* gb = (const float*)d_in[2];   // [8]
  const float* ew = (const float*)d_in[3];   // [8,1024,1024]
  const float* eb = (const float*)d_in[4];   // [8,1024]
  float* out = (float*)d_out;

  // ws: w[16384*8] fp32 (512 KB) | Xt bf16 (32 MB) | Bt bf16 (16 MB)
  float* wbuf = (float*)d_ws;
  unsigned short* xt = (unsigned short*)((char*)d_ws + (size_t)TOK * 8 * 4);
  unsigned short* bt = xt + (size_t)TOK * DDIM;

  gate_prep_x<<<TOK / 16, 256, 0, stream>>>(x, gw, gb, xt, wbuf);
  prep_w<<<dim3(DDIM / 32, DDIM / 32, NEXP), 256, 0, stream>>>(ew, bt);
  moe_gemm<<<dim3(256), 512, 0, stream>>>(xt, wbuf, bt, eb, out);
}

// Round 5
// 374.928 us; speedup vs baseline: 1.2136x; 1.0461x over previous
//
#include <hip/hip_runtime.h>
#include <stdint.h>

#define TOK   16384
#define DDIM  1024
#define NEXP  8
#define BM    256
#define BN    256
#define NKT   128           // 8 experts x 16 K-tiles (BK=64)
#define WEPS  1e-5f

typedef __attribute__((ext_vector_type(8))) short  short8;
typedef __attribute__((ext_vector_type(4))) float  floatx4;

// round-to-nearest-even f32 -> bf16 (normal-range data; no NaN path needed)
static __device__ __forceinline__ unsigned int bf16_rne(float f) {
  unsigned int u = __builtin_bit_cast(unsigned int, f);
  return (u + 0x7fffu + ((u >> 16) & 1u)) >> 16;
}
static __device__ __forceinline__ unsigned int pack2(float a, float b) {
  return bf16_rne(a) | (bf16_rne(b) << 16);
}

// ---------------------------------------------------------------------------
// Kernel 1: fp32 gate (w only). One wave per token, coalesced x reads.
// (R1-proven prep structure; prep experiments R2-R4 all regressed.)
// ---------------------------------------------------------------------------
__global__ __launch_bounds__(256) void gate_kernel(
    const float* __restrict__ x, const float* __restrict__ gw,
    const float* __restrict__ gb, float* __restrict__ wout) {
  int wave = threadIdx.x >> 6;
  int lane = threadIdx.x & 63;
  int t = blockIdx.x * 4 + wave;
  const float* xr = x + (size_t)t * DDIM;

  float acc[8];
#pragma unroll
  for (int e = 0; e < 8; ++e) acc[e] = 0.f;

#pragma unroll
  for (int i = 0; i < DDIM / 64; ++i) {
    int k = lane + 64 * i;
    float xv = xr[k];
    const float4* g = (const float4*)(gw + (size_t)k * 8);
    float4 g0 = g[0];
    float4 g1 = g[1];
    acc[0] += xv * g0.x; acc[1] += xv * g0.y;
    acc[2] += xv * g0.z; acc[3] += xv * g0.w;
    acc[4] += xv * g1.x; acc[5] += xv * g1.y;
    acc[6] += xv * g1.z; acc[7] += xv * g1.w;
  }
#pragma unroll
  for (int off = 32; off > 0; off >>= 1) {
#pragma unroll
    for (int e = 0; e < 8; ++e) acc[e] += __shfl_xor(acc[e], off, 64);
  }
  if (lane == 0) {
    float logit[8], m = -1e30f;
#pragma unroll
    for (int e = 0; e < 8; ++e) { logit[e] = acc[e] + gb[e]; m = fmaxf(m, logit[e]); }
    float p[8], s = 0.f;
#pragma unroll
    for (int e = 0; e < 8; ++e) { p[e] = expf(logit[e] - m); s += p[e]; }
    float wv[8], wsum = 0.f;
#pragma unroll
    for (int e = 0; e < 8; ++e) {
      float pr = p[e] / s;
      wv[e] = (pr >= 0.1f) ? pr : 0.f;
      wsum += wv[e];
    }
    float invw = (wsum == 0.f) ? 1.f : (1.f / wsum);
#pragma unroll
    for (int e = 0; e < 8; ++e) wout[(size_t)t * 8 + e] = wv[e] * invw;
  }
}

// ---------------------------------------------------------------------------
// Kernel 2: x fp32 [t][k] -> Xt bf16 chunk-tiled [t/16][k/32][16][32] with XOR
// bank swizzle (element (r,c) at r*32 + (c ^ (((r>>1)&3)*8))).
// ---------------------------------------------------------------------------
__global__ __launch_bounds__(256) void prep_x(
    const float* __restrict__ x, unsigned short* __restrict__ xt) {
  int g    = blockIdx.x * 4 + (threadIdx.x >> 6);  // chunk id
  int lane = threadIdx.x & 63;
  int m16 = g >> 5, k32 = g & 31;
  int r  = lane >> 2;        // token row within chunk
  int c4 = lane & 3;         // 8-element col group

  const float* src = x + (size_t)(m16 * 16 + r) * DDIM + k32 * 32 + c4 * 8;
  float4 v0 = *(const float4*)src;
  float4 v1 = *(const float4*)(src + 4);
  uint4 pk;
  pk.x = pack2(v0.x, v0.y); pk.y = pack2(v0.z, v0.w);
  pk.z = pack2(v1.x, v1.y); pk.w = pack2(v1.z, v1.w);
  int rot = ((r >> 1) & 3) * 8;
  *(uint4*)(xt + ((size_t)g << 9) + r * 32 + ((c4 * 8) ^ rot)) = pk;
}

// ---------------------------------------------------------------------------
// Kernel 3: expert_w fp32 [e][k][d] -> Bt bf16 chunk-tiled
// [e][d/16][k/32][16][32] with the same XOR swizzle (transpose via LDS tile).
// ---------------------------------------------------------------------------
__global__ __launch_bounds__(256) void prep_w(
    const float* __restrict__ ew, unsigned short* __restrict__ bt) {
  __shared__ float tile[32][33];
  int e  = blockIdx.z;
  int k0 = blockIdx.y * 32;
  int d0 = blockIdx.x * 32;
  int c4 = threadIdx.x & 7;
  int r  = threadIdx.x >> 3;

  const float* src = ew + ((size_t)e << 20) + (size_t)(k0 + r) * DDIM + d0 + c4 * 4;
  float4 v = *(const float4*)src;
  tile[r][c4 * 4 + 0] = v.x;
  tile[r][c4 * 4 + 1] = v.y;
  tile[r][c4 * 4 + 2] = v.z;
  tile[r][c4 * 4 + 3] = v.w;
  __syncthreads();

  uint2 pk;
  pk.x = pack2(tile[c4 * 4 + 0][r], tile[c4 * 4 + 1][r]);
  pk.y = pack2(tile[c4 * 4 + 2][r], tile[c4 * 4 + 3][r]);
  int d   = d0 + r;                  // output row (n), cols k = k0+c4*4 .. +3
  int d16 = d >> 4, r16 = d & 15, k32 = k0 >> 5, kc = c4 * 4;
  int rot = ((r16 >> 1) & 3) * 8;
  *(uint2*)(bt + ((((size_t)e * 64 + d16) * 32 + k32) << 9) + r16 * 32 + (kc ^ rot)) = pk;
}

// ---------------------------------------------------------------------------
// Kernel 4: MoE GEMM. R1 structure MINUS the per-phase opening barrier:
// each phase is now {ds_read frags | stage DMA | setprio MFMA cluster | SBAR}.
// Rationale: the opening SBAR+lgkmcnt(0) forced all-waves lockstep, so LDS
// read time (~1.5-2.3K cyc/tile) ADDED to MFMA time (2482 cyc/tile) instead
// of overlapping across waves. Removal is race-free because:
//  (1) frag-read retirement before each closing SBAR is forced by data dep
//      (reads feed this phase's MFMAs, which precede the barrier; compiler's
//      counted lgkmcnt retires them before the last MFMA issues);
//  (2) every stage DMA targets a region whose last reads were certified >=2
//      closing barriers earlier (A0:4, A1:3, B0/B1:2 phases of margin);
//  (3) reads of tile kt start only after p4(kt-1)'s WAITVM4+SBAR, which
//      certifies ALL waves' tile-kt DMA chunks landed (unchanged).
// Counted vmcnt(4) once per tile (never 0 in loop); Horner w-folding; no
// plain VMEM in the main loop; XCD-aware block mapping.
// ---------------------------------------------------------------------------
#define SBAR()      __builtin_amdgcn_s_barrier()
#define WAITVM4()   asm volatile("s_waitcnt vmcnt(4)" ::: "memory")
#define WAITVM0()   asm volatile("s_waitcnt vmcnt(0)" ::: "memory")

__global__ __launch_bounds__(512, 2) void moe_gemm(
    const unsigned short* __restrict__ xt,  // [1024][32][16][32] bf16 swizzled
    const float* __restrict__ w,            // [16384][8]
    const unsigned short* __restrict__ bt,  // [8][64][32][16][32] bf16 swizzled
    const float* __restrict__ eb, float* __restrict__ out) {
  // 2 x 64KB tile buffers (A 32 chunks + B 32 chunks, 1KB each) + w tables
  __shared__ __align__(16) unsigned char lds[147456];
  float* wtab = (float*)(lds + 131072);   // [256][8] raw gate weights
  float* rtab = (float*)(lds + 139264);   // [8][256]: e<7 ratio w'_e/w'_{e+1}; [7]=w'_7

  const int tid  = threadIdx.x;
  const int wave = tid >> 6;
  const int lane = tid & 63;

  // XCD-aware mapping: 256 blocks, xcd = wgid%8 owns contiguous bm chunk
  const int wgid = blockIdx.x;
  const int xcd  = wgid & 7;
  const int idx  = wgid >> 3;              // 0..31
  const int bm0  = (xcd * 8 + (idx & 7)) * BM;
  const int bn0  = (idx >> 3) * BN;
  const int bm16 = bm0 >> 4;
  const int bn16 = bn0 >> 4;

  const int wm  = (wave >> 2) * 128;       // wave's A half (2M x 4N wave grid)
  const int wn  = (wave & 3) * 64;
  const int fr  = lane & 15;
  const int q8  = (lane >> 4) * 8;
  const int qby = (fr * 32 + (q8 ^ (((fr >> 1) & 3) * 8))) * 2;  // swizzled byte off

  // ---- prologue: w tables (ALL plain VMEM drained before pipeline starts) ----
  ((float4*)wtab)[tid] = ((const float4*)(w + (size_t)bm0 * 8))[tid];
  __syncthreads();
  {
    const int t  = tid & 255;
    const int e0 = (tid >> 8) * 4;
#pragma unroll
    for (int i = 0; i < 4; ++i) {
      int e = e0 + i;
      float wc = fmaxf(wtab[t * 8 + e], WEPS);
      float r  = wc;
      if (e < 7) r = wc * __builtin_amdgcn_rcpf(fmaxf(wtab[t * 8 + e + 1], WEPS));
      rtab[e * 256 + t] = r;
    }
  }
  __syncthreads();

  // half-tile stagers: 2 x global_load_lds(16B) per wave; wave w owns chunk h*8+w
  auto stageA = [&](int h, int kt) {
    if (kt >= NKT) return;
    const int b = kt & 1;
    const size_t mc = (size_t)(bm16 + h * 8 + wave) * 32 + (kt & 15) * 2;
#pragma unroll
    for (int ks = 0; ks < 2; ++ks) {
      __builtin_amdgcn_global_load_lds(
          (const __attribute__((address_space(1))) unsigned int*)(xt + ((mc + ks) << 9) + lane * 8),
          (__attribute__((address_space(3))) unsigned int*)(lds + b * 65536 + ((h * 8 + wave) * 2 + ks) * 1024),
          16, 0, 0);
    }
  };
  auto stageB = [&](int h, int kt) {
    if (kt >= NKT) return;
    const int b = kt & 1;
    const size_t dc = (size_t)((kt >> 4) * 64 + bn16 + h * 8 + wave) * 32 + (kt & 15) * 2;
#pragma unroll
    for (int ks = 0; ks < 2; ++ks) {
      __builtin_amdgcn_global_load_lds(
          (const __attribute__((address_space(1))) unsigned int*)(bt + ((dc + ks) << 9) + lane * 8),
          (__attribute__((address_space(3))) unsigned int*)(lds + b * 65536 + 32768 + ((h * 8 + wave) * 2 + ks) * 1024),
          16, 0, 0);
    }
  };
  auto AF = [&](int b, int mh, int mi, int ks) -> short8 {
    return *(const short8*)(lds + b * 65536 +
        ((((wave >> 2) * 8 + mh * 4 + mi) * 2 + ks) << 10) + qby);
  };
  auto BF = [&](int b, int nh, int ni, int ks) -> short8 {
    return *(const short8*)(lds + b * 65536 + 32768 +
        ((((wave & 3) * 4 + nh * 2 + ni) * 2 + ks) << 10) + qby);
  };

  floatx4 acc[8][4];
#pragma unroll
  for (int mi = 0; mi < 8; ++mi)
#pragma unroll
    for (int ni = 0; ni < 4; ++ni) acc[mi][ni] = (floatx4)0.f;

  // pipeline prologue: tile0 complete + B halves of tile1 left in flight
  stageA(0, 0); stageA(1, 0); stageB(0, 0); stageB(1, 0);
  stageB(0, 1); stageB(1, 1);
  WAITVM4();          // 12 issued, <=4 outstanding -> tile0's 8 landed
  SBAR();

  auto tile = [&](int kt, int b) {
    short8 af[4][2], b0[2][2], b1[2][2];

    // -- phase 1: Q(m-half0, n-half0) --
#pragma unroll
    for (int mi = 0; mi < 4; ++mi) { af[mi][0] = AF(b, 0, mi, 0); af[mi][1] = AF(b, 0, mi, 1); }
#pragma unroll
    for (int ni = 0; ni < 2; ++ni) { b0[ni][0] = BF(b, 0, ni, 0); b0[ni][1] = BF(b, 0, ni, 1); }
    stageA(0, kt + 1);
    __builtin_amdgcn_s_setprio(1);
#pragma unroll
    for (int mi = 0; mi < 4; ++mi)
#pragma unroll
      for (int ni = 0; ni < 2; ++ni)
#pragma unroll
        for (int ks = 0; ks < 2; ++ks)
          acc[mi][ni] = __builtin_amdgcn_mfma_f32_16x16x32_bf16(af[mi][ks], b0[ni][ks], acc[mi][ni], 0, 0, 0);
    __builtin_amdgcn_s_setprio(0);
    SBAR();

    // -- phase 2: Q(m-half0, n-half1) --
#pragma unroll
    for (int ni = 0; ni < 2; ++ni) { b1[ni][0] = BF(b, 1, ni, 0); b1[ni][1] = BF(b, 1, ni, 1); }
    stageA(1, kt + 1);
    __builtin_amdgcn_s_setprio(1);
#pragma unroll
    for (int mi = 0; mi < 4; ++mi)
#pragma unroll
      for (int ni = 0; ni < 2; ++ni)
#pragma unroll
        for (int ks = 0; ks < 2; ++ks)
          acc[mi][ni + 2] = __builtin_amdgcn_mfma_f32_16x16x32_bf16(af[mi][ks], b1[ni][ks], acc[mi][ni + 2], 0, 0, 0);
    __builtin_amdgcn_s_setprio(0);
    SBAR();

    // -- phase 3: Q(m-half1, n-half0) --
#pragma unroll
    for (int mi = 0; mi < 4; ++mi) { af[mi][0] = AF(b, 1, mi, 0); af[mi][1] = AF(b, 1, mi, 1); }
    stageB(0, kt + 2);
    __builtin_amdgcn_s_setprio(1);
#pragma unroll
    for (int mi = 0; mi < 4; ++mi)
#pragma unroll
      for (int ni = 0; ni < 2; ++ni)
#pragma unroll
        for (int ks = 0; ks < 2; ++ks)
          acc[mi + 4][ni] = __builtin_amdgcn_mfma_f32_16x16x32_bf16(af[mi][ks], b0[ni][ks], acc[mi + 4][ni], 0, 0, 0);
    __builtin_amdgcn_s_setprio(0);
    SBAR();

    // -- phase 4: Q(m-half1, n-half1); tile-boundary counted wait --
    stageB(1, kt + 2);
    __builtin_amdgcn_s_setprio(1);
#pragma unroll
    for (int mi = 0; mi < 4; ++mi)
#pragma unroll
      for (int ni = 0; ni < 2; ++ni)
#pragma unroll
        for (int ks = 0; ks < 2; ++ks)
          acc[mi + 4][ni + 2] = __builtin_amdgcn_mfma_f32_16x16x32_bf16(af[mi][ks], b1[ni][ks], acc[mi + 4][ni + 2], 0, 0, 0);
    __builtin_amdgcn_s_setprio(0);
    if (kt < NKT - 2) { WAITVM4(); } else { WAITVM0(); }
    SBAR();

    // -- Horner boundary: acc *= w'_e / w'_{e+1} (from LDS table) --
    if ((kt & 15) == 15 && kt < NKT - 1) {
      const int e  = kt >> 4;
      const int rb = e * 256 + wm + (lane >> 4) * 4;
#pragma unroll
      for (int mi = 0; mi < 8; ++mi) {
        floatx4 rv = *(const floatx4*)(rtab + rb + mi * 16);
#pragma unroll
        for (int ni = 0; ni < 4; ++ni)
#pragma unroll
          for (int rr = 0; rr < 4; ++rr) acc[mi][ni][rr] *= rv[rr];
      }
    }
  };

  for (int kt2 = 0; kt2 < NKT / 2; ++kt2) {
    tile(kt2 * 2, 0);
    tile(kt2 * 2 + 1, 1);
  }

  // keep the epilogue VMEM (eb loads) from hoisting into the counted pipeline
  asm volatile("" ::: "memory");

  // ---- epilogue: out = acc * w'_7 + sum_e w_e * eb_e ----
  float ebv[8][4];
#pragma unroll
  for (int e = 0; e < 8; ++e)
#pragma unroll
    for (int ni = 0; ni < 4; ++ni)
      ebv[e][ni] = eb[(size_t)e * DDIM + bn0 + wn + ni * 16 + fr];

#pragma unroll
  for (int mi = 0; mi < 8; ++mi) {
    const int tl0 = wm + mi * 16 + (lane >> 4) * 4;
    floatx4 w7v = *(const floatx4*)(rtab + 7 * 256 + tl0);
#pragma unroll
    for (int rr = 0; rr < 4; ++rr) {
      const int tl = tl0 + rr;
      floatx4 w0 = *(const floatx4*)(wtab + tl * 8);
      floatx4 w1 = *(const floatx4*)(wtab + tl * 8 + 4);
      float* orow = out + (size_t)(bm0 + tl) * DDIM + bn0 + wn + fr;
#pragma unroll
      for (int ni = 0; ni < 4; ++ni) {
        float bias = w0[0] * ebv[0][ni] + w0[1] * ebv[1][ni] +
                     w0[2] * ebv[2][ni] + w0[3] * ebv[3][ni] +
                     w1[0] * ebv[4][ni] + w1[1] * ebv[5][ni] +
                     w1[2] * ebv[6][ni] + w1[3] * ebv[7][ni];
        orow[ni * 16] = acc[mi][ni][rr] * w7v[rr] + bias;
      }
    }
  }
}

// ---------------------------------------------------------------------------
extern "C" void kernel_launch(void* const* d_in, const int* in_sizes, int n_in,
                              void* d_out, int out_size, void* d_ws, size_t ws_size,
                              hipStream_t stream) {
  const float* x  = (const float*)d_in[0];   // [4,4096,1024]
  const float* gw = (const float*)d_in[1];   // [1024,8]
  const float* gb = (const float*)d_in[2];   // [8]
  const float* ew = (const float*)d_in[3];   // [8,1024,1024]
  const float* eb = (const float*)d_in[4];   // [8,1024]
  float* out = (float*)d_out;

  // ws: w[16384*8] fp32 (512 KB) | Xt bf16 (32 MB) | Bt bf16 (16 MB)
  float* wbuf = (float*)d_ws;
  unsigned short* xt = (unsigned short*)((char*)d_ws + (size_t)TOK * 8 * 4);
  unsigned short* bt = xt + (size_t)TOK * DDIM;

  gate_kernel<<<TOK / 4, 256, 0, stream>>>(x, gw, gb, wbuf);
  prep_x<<<(TOK / 16) * 32 / 4, 256, 0, stream>>>(x, xt);
  prep_w<<<dim3(DDIM / 32, DDIM / 32, NEXP), 256, 0, stream>>>(ew, bt);
  moe_gemm<<<dim3(256), 512, 0, stream>>>(xt, wbuf, bt, eb, out);
}